// Round 1
// baseline (344.261 us; speedup 1.0000x reference)
//
#include <hip/hip_runtime.h>
#include <hip/hip_bf16.h>

#define DIM 512
#define NH 8
#define DH 64
#define HW 1024     // 32*32
#define NPIX 8192   // 8*32*32

typedef __attribute__((ext_vector_type(8))) short s16x8;
typedef __attribute__((ext_vector_type(4))) float f32x4;

union B8 { s16x8 v; __hip_bfloat16 h[8]; };

// ---- kernel P: weight prep.
// blocks [0,128):   wq -> wqb (bf16, same [out][in] layout)
// blocks [128,256): wk -> wkb
// blocks [256,272): wvt[c*8+n] = sum_d wv[n*64+d][c]  (column sums, [c][n] layout)
__global__ __launch_bounds__(256) void k_prep(const float* __restrict__ wq,
                                              const float* __restrict__ wk,
                                              const float* __restrict__ wv,
                                              short* __restrict__ wqb,
                                              short* __restrict__ wkb,
                                              float* __restrict__ wvt) {
  const int b = blockIdx.x, t = threadIdx.x;
  if (b < 256) {
    const int half = b >> 7;                 // 0: wq, 1: wk
    const float* src = half ? wk : wq;
    short* dst = half ? wkb : wqb;
    const int idx = ((b & 127) * 256 + t) * 8;
    const f32x4 a = *(const f32x4*)(src + idx);
    const f32x4 c = *(const f32x4*)(src + idx + 4);
    B8 u;
#pragma unroll
    for (int m = 0; m < 4; ++m) { u.h[m] = __float2bfloat16(a[m]); u.h[4 + m] = __float2bfloat16(c[m]); }
    *(s16x8*)(dst + idx) = u.v;
  } else {
    const int i = b - 256;
    const int n = t >> 5, c = i * 32 + (t & 31);   // lanes 0-31: consecutive c -> coalesced
    const float* base = wv + (size_t)n * DH * DIM + c;
    float acc = 0.f;
#pragma unroll 8
    for (int d = 0; d < DH; ++d) acc += base[(size_t)d * DIM];
    wvt[c * NH + n] = acc;
  }
}

// ---- kernel XV: fused x->bf16 conversion + v-sum.
// one wave per pixel: xb[p][c] = bf16(x[p][c]);  vs[(b*8+n)*1024+xy] = sum_c x[p][c]*wvt[c][n]
__global__ __launch_bounds__(256) void k_xv(const float* __restrict__ x,
                                            const float* __restrict__ wvt,
                                            short* __restrict__ xb,
                                            float* __restrict__ vs) {
  const int t = threadIdx.x, wave = t >> 6, lane = t & 63;
  const int p = blockIdx.x * 4 + wave;
  const float* xp = x + (size_t)p * DIM + lane * 8;
  const f32x4 x0 = *(const f32x4*)(xp);
  const f32x4 x1 = *(const f32x4*)(xp + 4);
  float xf[8];
  B8 u;
#pragma unroll
  for (int j = 0; j < 4; ++j) {
    xf[j] = x0[j]; xf[4 + j] = x1[j];
    u.h[j] = __float2bfloat16(x0[j]); u.h[4 + j] = __float2bfloat16(x1[j]);
  }
  *(s16x8*)(xb + (size_t)p * DIM + lane * 8) = u.v;    // 1 KB/wave contiguous
  float acc[8] = {0.f,0.f,0.f,0.f,0.f,0.f,0.f,0.f};
  const float* wp = wvt + lane * 64;                   // c=8l..8l+8, n=0..8
#pragma unroll
  for (int cc = 0; cc < 8; ++cc) {
    const f32x4 a = *(const f32x4*)(wp + cc * 8);
    const f32x4 b = *(const f32x4*)(wp + cc * 8 + 4);
#pragma unroll
    for (int j = 0; j < 4; ++j) { acc[j] += xf[cc] * a[j]; acc[4 + j] += xf[cc] * b[j]; }
  }
#pragma unroll
  for (int off = 32; off >= 1; off >>= 1) {
#pragma unroll
    for (int j = 0; j < 8; ++j) acc[j] += __shfl_xor(acc[j], off, 64);
  }
  if (lane == 0) {
    const int b_ = p >> 10, xy = p & 1023;
#pragma unroll
    for (int j = 0; j < 8; ++j) vs[(size_t)(b_ * NH + j) * HW + xy] = acc[j];
  }
}

// ---- kernel QK: LDS-free q/k projection + per-pixel head dot + softmax.
// grid 256 blocks (32 pixels = one softmax w-row group), block 512 (8 waves, wave = head).
// MFMA fragments loaded DIRECTLY from global bf16 (A: 8 consecutive k of a pixel row,
// B: 8 consecutive k of a weight row — both contiguous 16B). wqb/wkb (1 MB) are
// L2-resident on every XCD; no staging, no main-loop barriers.
__global__ __launch_bounds__(512) void k_qk(const short* __restrict__ xb,
                                            const short* __restrict__ wqb,
                                            const short* __restrict__ wkb,
                                            float* __restrict__ sw) {
  __shared__ float sm[NH * 32];
  const int t = threadIdx.x;
  const int head = t >> 6, lane = t & 63;
  const int lrow = lane & 15, quad = lane >> 4;
  const int pix0 = blockIdx.x * 32;

  const short* xr0 = xb + (size_t)(pix0 + lrow) * DIM + quad * 8;
  const short* xr1 = xr0 + 16 * DIM;
  const short* qb = wqb + (size_t)(head * DH + lrow) * DIM + quad * 8;
  const short* kb = wkb + (size_t)(head * DH + lrow) * DIM + quad * 8;

  f32x4 accq[2][4], acck[2][4];
#pragma unroll
  for (int s = 0; s < 2; ++s)
#pragma unroll
    for (int o = 0; o < 4; ++o) { accq[s][o] = (f32x4)0.f; acck[s][o] = (f32x4)0.f; }

#pragma unroll 2
  for (int ks = 0; ks < 16; ++ks) {
    const int off = ks * 32;
    const s16x8 a0 = *(const s16x8*)(xr0 + off);
    const s16x8 a1 = *(const s16x8*)(xr1 + off);
#pragma unroll
    for (int o = 0; o < 4; ++o) {
      const s16x8 bq = *(const s16x8*)(qb + o * 16 * DIM + off);
      accq[0][o] = __builtin_amdgcn_mfma_f32_16x16x32_bf16(a0, bq, accq[0][o], 0, 0, 0);
      accq[1][o] = __builtin_amdgcn_mfma_f32_16x16x32_bf16(a1, bq, accq[1][o], 0, 0, 0);
      const s16x8 bk = *(const s16x8*)(kb + o * 16 * DIM + off);
      acck[0][o] = __builtin_amdgcn_mfma_f32_16x16x32_bf16(a0, bk, acck[0][o], 0, 0, 0);
      acck[1][o] = __builtin_amdgcn_mfma_f32_16x16x32_bf16(a1, bk, acck[1][o], 0, 0, 0);
    }
  }

  // per-row dot over the 64 head channels: sum 4 col-subtiles + 16 col-lanes.
  // C layout: col = lane&15 (out-ch), row = quad*4 + reg (pixel) — reduce over lrow.
#pragma unroll
  for (int s = 0; s < 2; ++s) {
#pragma unroll
    for (int j = 0; j < 4; ++j) {
      float pr = accq[s][0][j] * acck[s][0][j] + accq[s][1][j] * acck[s][1][j]
               + accq[s][2][j] * acck[s][2][j] + accq[s][3][j] * acck[s][3][j];
      pr += __shfl_xor(pr, 1, 64);
      pr += __shfl_xor(pr, 2, 64);
      pr += __shfl_xor(pr, 4, 64);
      pr += __shfl_xor(pr, 8, 64);
      if (lrow == 0) sm[head * 32 + s * 16 + quad * 4 + j] = pr * 0.125f;  // scale = 1/8
    }
  }
  __syncthreads();

  // softmax over the 32 w-positions; wave `head` handles its own row.
  // both 32-lane halves hold identical copies -> xor 1..16 reduces correctly.
  const float v = sm[head * 32 + (lane & 31)];
  float m = v;
#pragma unroll
  for (int off = 1; off <= 16; off <<= 1) m = fmaxf(m, __shfl_xor(m, off, 64));
  const float e = __expf(v - m);
  float se = e;
#pragma unroll
  for (int off = 1; off <= 16; off <<= 1) se += __shfl_xor(se, off, 64);
  if (lane < 32) {
    const int p = pix0 + lane;
    const int b_ = p >> 10, hw = p & 1023;
    sw[(size_t)(b_ * NH + head) * HW + hw] = e / se;
  }
}

// ---- kernel D: out[bn][hw][xy] = sw[bn][hw] * vs[bn][xy], FP32 out, nt float4 stores.
// grid (32 row-groups of 32, 64 bn), block 256; each block writes a contiguous 128 KB panel.
__global__ __launch_bounds__(256) void k_out(const float* __restrict__ sw,
                                             const float* __restrict__ vs,
                                             float* __restrict__ out) {
  __shared__ float swl[32];
  const int bn = blockIdx.y;
  const int row0 = blockIdx.x * 32;
  const int t = threadIdx.x;
  if (t < 32) swl[t] = sw[(size_t)bn * HW + row0 + t];
  __syncthreads();
  const f32x4 va = *(const f32x4*)(vs + (size_t)bn * HW + t * 4);
  float* op = out + (size_t)bn * HW * HW + (size_t)row0 * HW + t * 4;
#pragma unroll 4
  for (int r = 0; r < 32; ++r) {
    const float w = swl[r];
    f32x4 o;
#pragma unroll
    for (int j = 0; j < 4; ++j) o[j] = w * va[j];
    __builtin_nontemporal_store(o, (f32x4*)(op + (size_t)r * HW));
  }
}

extern "C" void kernel_launch(void* const* d_in, const int* in_sizes, int n_in,
                              void* d_out, int out_size, void* d_ws, size_t ws_size,
                              hipStream_t stream) {
  const float* x  = (const float*)d_in[0];
  const float* wq = (const float*)d_in[1];
  const float* wk = (const float*)d_in[2];
  const float* wv = (const float*)d_in[3];
  float* out = (float*)d_out;

  float* wvt = (float*)d_ws;                 // 4096 floats   [c][n]
  float* vs  = wvt + 4096;                   // 65536 floats  [bn][xy]
  float* sw  = vs + 65536;                   // 65536 floats  [bn][hw]
  short* xb  = (short*)(sw + 65536);         // 8192*512 bf16 (8 MB), 16B-aligned
  short* wqb = xb + (size_t)NPIX * DIM;      // 512*512 bf16
  short* wkb = wqb + DIM * DIM;              // 512*512 bf16

  hipLaunchKernelGGL(k_prep, dim3(272), dim3(256), 0, stream, wq, wk, wv, wqb, wkb, wvt);
  hipLaunchKernelGGL(k_xv, dim3(NPIX / 4), dim3(256), 0, stream, x, wvt, xb, vs);
  hipLaunchKernelGGL(k_qk, dim3(NPIX / 32), dim3(512), 0, stream, xb, wqb, wkb, sw);
  hipLaunchKernelGGL(k_out, dim3(32, 64), dim3(256), 0, stream, sw, vs, out);
}

// Round 2
// 337.818 us; speedup vs baseline: 1.0191x; 1.0191x over previous
//
#include <hip/hip_runtime.h>
#include <hip/hip_bf16.h>

#define DIM 512
#define NH 8
#define DH 64
#define HW 1024     // 32*32
#define NPIX 8192   // 8*32*32

typedef __attribute__((ext_vector_type(8))) short s16x8;
typedef __attribute__((ext_vector_type(4))) float f32x4;

union B8 { s16x8 v; __hip_bfloat16 h[8]; };

// ---- kernel P: weight prep.
// blocks [0,128):   wq -> wqb (bf16, same [out][in] layout)
// blocks [128,256): wk -> wkb
// blocks [256,272): wvt[c*8+n] = sum_d wv[n*64+d][c]  (column sums, [c][n] layout)
__global__ __launch_bounds__(256) void k_prep(const float* __restrict__ wq,
                                              const float* __restrict__ wk,
                                              const float* __restrict__ wv,
                                              short* __restrict__ wqb,
                                              short* __restrict__ wkb,
                                              float* __restrict__ wvt) {
  const int b = blockIdx.x, t = threadIdx.x;
  if (b < 256) {
    const int half = b >> 7;                 // 0: wq, 1: wk
    const float* src = half ? wk : wq;
    short* dst = half ? wkb : wqb;
    const int idx = ((b & 127) * 256 + t) * 8;
    const f32x4 a = *(const f32x4*)(src + idx);
    const f32x4 c = *(const f32x4*)(src + idx + 4);
    B8 u;
#pragma unroll
    for (int m = 0; m < 4; ++m) { u.h[m] = __float2bfloat16(a[m]); u.h[4 + m] = __float2bfloat16(c[m]); }
    *(s16x8*)(dst + idx) = u.v;
  } else {
    const int i = b - 256;
    const int n = t >> 5, c = i * 32 + (t & 31);   // lanes 0-31: consecutive c -> coalesced
    const float* base = wv + (size_t)n * DH * DIM + c;
    float acc = 0.f;
#pragma unroll 8
    for (int d = 0; d < DH; ++d) acc += base[(size_t)d * DIM];
    wvt[c * NH + n] = acc;
  }
}

// ---- kernel XV: fused x->bf16 conversion + v-sum.
// one wave per pixel: xb[p][c] = bf16(x[p][c]);  vs[(b*8+n)*1024+xy] = sum_c x[p][c]*wvt[c][n]
__global__ __launch_bounds__(256) void k_xv(const float* __restrict__ x,
                                            const float* __restrict__ wvt,
                                            short* __restrict__ xb,
                                            float* __restrict__ vs) {
  const int t = threadIdx.x, wave = t >> 6, lane = t & 63;
  const int p = blockIdx.x * 4 + wave;
  const float* xp = x + (size_t)p * DIM + lane * 8;
  const f32x4 x0 = *(const f32x4*)(xp);
  const f32x4 x1 = *(const f32x4*)(xp + 4);
  float xf[8];
  B8 u;
#pragma unroll
  for (int j = 0; j < 4; ++j) {
    xf[j] = x0[j]; xf[4 + j] = x1[j];
    u.h[j] = __float2bfloat16(x0[j]); u.h[4 + j] = __float2bfloat16(x1[j]);
  }
  *(s16x8*)(xb + (size_t)p * DIM + lane * 8) = u.v;    // 1 KB/wave contiguous
  float acc[8] = {0.f,0.f,0.f,0.f,0.f,0.f,0.f,0.f};
  const float* wp = wvt + lane * 64;                   // c=8l..8l+8, n=0..8
#pragma unroll
  for (int cc = 0; cc < 8; ++cc) {
    const f32x4 a = *(const f32x4*)(wp + cc * 8);
    const f32x4 b = *(const f32x4*)(wp + cc * 8 + 4);
#pragma unroll
    for (int j = 0; j < 4; ++j) { acc[j] += xf[cc] * a[j]; acc[4 + j] += xf[cc] * b[j]; }
  }
#pragma unroll
  for (int off = 32; off >= 1; off >>= 1) {
#pragma unroll
    for (int j = 0; j < 8; ++j) acc[j] += __shfl_xor(acc[j], off, 64);
  }
  if (lane == 0) {
    const int b_ = p >> 10, xy = p & 1023;
#pragma unroll
    for (int j = 0; j < 8; ++j) vs[(size_t)(b_ * NH + j) * HW + xy] = acc[j];
  }
}

// ---- kernel QKO: fused q/k projection (MFMA, direct-global bf16 fragments) +
// per-pixel head dot + softmax + OUTPUT WRITE.
// grid (256 pixel-groups of 32, 2 head-halves), block 256 (4 waves; wave = one head).
// Per block: 32 pixels x 4 heads. Softmax over the 32-w group is wave-local.
// Store phase: each wave streams its head's 32x1024 f32 panel = prob[r]*vs[bn].
__global__ __launch_bounds__(256) void k_qko(const short* __restrict__ xb,
                                             const short* __restrict__ wqb,
                                             const short* __restrict__ wkb,
                                             const float* __restrict__ vs,
                                             float* __restrict__ out) {
  __shared__ float sm[4 * 32];
  __shared__ float probs[4 * 32];
  const int t = threadIdx.x;
  const int wave = t >> 6, lane = t & 63;
  const int lrow = lane & 15, quad = lane >> 4;
  const int pix0 = blockIdx.x * 32;
  const int head = blockIdx.y * 4 + wave;
  const int b_ = pix0 >> 10, hw0 = pix0 & 1023;
  const int bn = b_ * NH + head;

  // prefetch vs panel row for the store phase (16 floats/lane, covers xy 0..1023)
  f32x4 vsr[4];
  const float* vp = vs + (size_t)bn * HW + lane * 4;
#pragma unroll
  for (int c = 0; c < 4; ++c) vsr[c] = *(const f32x4*)(vp + c * 256);

  const short* xr0 = xb + (size_t)(pix0 + lrow) * DIM + quad * 8;
  const short* xr1 = xr0 + 16 * DIM;
  const short* qb = wqb + (size_t)(head * DH + lrow) * DIM + quad * 8;
  const short* kb = wkb + (size_t)(head * DH + lrow) * DIM + quad * 8;

  f32x4 accq[2][4], acck[2][4];
#pragma unroll
  for (int s = 0; s < 2; ++s)
#pragma unroll
    for (int o = 0; o < 4; ++o) { accq[s][o] = (f32x4)0.f; acck[s][o] = (f32x4)0.f; }

#pragma unroll 2
  for (int ks = 0; ks < 16; ++ks) {
    const int off = ks * 32;
    const s16x8 a0 = *(const s16x8*)(xr0 + off);
    const s16x8 a1 = *(const s16x8*)(xr1 + off);
#pragma unroll
    for (int o = 0; o < 4; ++o) {
      const s16x8 bq = *(const s16x8*)(qb + o * 16 * DIM + off);
      accq[0][o] = __builtin_amdgcn_mfma_f32_16x16x32_bf16(a0, bq, accq[0][o], 0, 0, 0);
      accq[1][o] = __builtin_amdgcn_mfma_f32_16x16x32_bf16(a1, bq, accq[1][o], 0, 0, 0);
      const s16x8 bk = *(const s16x8*)(kb + o * 16 * DIM + off);
      acck[0][o] = __builtin_amdgcn_mfma_f32_16x16x32_bf16(a0, bk, acck[0][o], 0, 0, 0);
      acck[1][o] = __builtin_amdgcn_mfma_f32_16x16x32_bf16(a1, bk, acck[1][o], 0, 0, 0);
    }
  }

  // per-row dot over the 64 head channels: sum 4 col-subtiles + 16 col-lanes.
  // C layout: col = lane&15 (out-ch), row = quad*4 + reg (pixel) — reduce over lrow.
#pragma unroll
  for (int s = 0; s < 2; ++s) {
#pragma unroll
    for (int j = 0; j < 4; ++j) {
      float pr = accq[s][0][j] * acck[s][0][j] + accq[s][1][j] * acck[s][1][j]
               + accq[s][2][j] * acck[s][2][j] + accq[s][3][j] * acck[s][3][j];
      pr += __shfl_xor(pr, 1, 64);
      pr += __shfl_xor(pr, 2, 64);
      pr += __shfl_xor(pr, 4, 64);
      pr += __shfl_xor(pr, 8, 64);
      if (lrow == 0) sm[wave * 32 + s * 16 + quad * 4 + j] = pr * 0.125f;  // scale = 1/8
    }
  }
  __syncthreads();

  // softmax over the 32 w-positions; both 32-lane halves hold identical copies.
  const float v = sm[wave * 32 + (lane & 31)];
  float m = v;
#pragma unroll
  for (int off = 1; off <= 16; off <<= 1) m = fmaxf(m, __shfl_xor(m, off, 64));
  const float e = __expf(v - m);
  float se = e;
#pragma unroll
  for (int off = 1; off <= 16; off <<= 1) se += __shfl_xor(se, off, 64);
  if (lane < 32) probs[wave * 32 + lane] = e / se;
  __syncthreads();

  // store phase: out[bn][hw0+r][xy] = probs[r] * vs[bn][xy], NT float4 stores.
  // wave covers xy via 4 chunks of 256: xy = c*256 + lane*4 -> 1 KB contiguous/store.
  float* op = out + (size_t)bn * HW * HW + (size_t)hw0 * HW + lane * 4;
#pragma unroll 4
  for (int r = 0; r < 32; ++r) {
    const float w = probs[wave * 32 + r];
    float* orow = op + (size_t)r * HW;
#pragma unroll
    for (int c = 0; c < 4; ++c) {
      f32x4 o;
#pragma unroll
      for (int j = 0; j < 4; ++j) o[j] = w * vsr[c][j];
      __builtin_nontemporal_store(o, (f32x4*)(orow + c * 256));
    }
  }
}

extern "C" void kernel_launch(void* const* d_in, const int* in_sizes, int n_in,
                              void* d_out, int out_size, void* d_ws, size_t ws_size,
                              hipStream_t stream) {
  const float* x  = (const float*)d_in[0];
  const float* wq = (const float*)d_in[1];
  const float* wk = (const float*)d_in[2];
  const float* wv = (const float*)d_in[3];
  float* out = (float*)d_out;

  float* wvt = (float*)d_ws;                 // 4096 floats   [c][n]
  float* vs  = wvt + 4096;                   // 65536 floats  [bn][xy]
  short* xb  = (short*)(vs + 65536);         // 8192*512 bf16 (8 MB), 16B-aligned
  short* wqb = xb + (size_t)NPIX * DIM;      // 512*512 bf16
  short* wkb = wqb + DIM * DIM;              // 512*512 bf16

  hipLaunchKernelGGL(k_prep, dim3(272), dim3(256), 0, stream, wq, wk, wv, wqb, wkb, wvt);
  hipLaunchKernelGGL(k_xv, dim3(NPIX / 4), dim3(256), 0, stream, x, wvt, xb, vs);
  hipLaunchKernelGGL(k_qko, dim3(NPIX / 32, 2), dim3(256), 0, stream, xb, wqb, wkb, vs, out);
}

// Round 3
// 336.187 us; speedup vs baseline: 1.0240x; 1.0048x over previous
//
#include <hip/hip_runtime.h>
#include <hip/hip_bf16.h>

#define DIM 512
#define NH 8
#define DH 64
#define HW 1024     // 32*32
#define NPIX 8192   // 8*32*32

typedef __attribute__((ext_vector_type(8))) short s16x8;
typedef __attribute__((ext_vector_type(4))) float f32x4;

union B8 { s16x8 v; __hip_bfloat16 h[8]; };

// ---- kernel P: weight prep.
// blocks [0,128):   wq -> wqb (bf16, same [out][in] layout)
// blocks [128,256): wk -> wkb
// blocks [256,272): wvt[c*8+n] = sum_d wv[n*64+d][c]  (column sums, [c][n] layout)
__global__ __launch_bounds__(256) void k_prep(const float* __restrict__ wq,
                                              const float* __restrict__ wk,
                                              const float* __restrict__ wv,
                                              short* __restrict__ wqb,
                                              short* __restrict__ wkb,
                                              float* __restrict__ wvt) {
  const int b = blockIdx.x, t = threadIdx.x;
  if (b < 256) {
    const int half = b >> 7;                 // 0: wq, 1: wk
    const float* src = half ? wk : wq;
    short* dst = half ? wkb : wqb;
    const int idx = ((b & 127) * 256 + t) * 8;
    const f32x4 a = *(const f32x4*)(src + idx);
    const f32x4 c = *(const f32x4*)(src + idx + 4);
    B8 u;
#pragma unroll
    for (int m = 0; m < 4; ++m) { u.h[m] = __float2bfloat16(a[m]); u.h[4 + m] = __float2bfloat16(c[m]); }
    *(s16x8*)(dst + idx) = u.v;
  } else {
    const int i = b - 256;
    const int n = t >> 5, c = i * 32 + (t & 31);   // lanes 0-31: consecutive c -> coalesced
    const float* base = wv + (size_t)n * DH * DIM + c;
    float acc = 0.f;
#pragma unroll 8
    for (int d = 0; d < DH; ++d) acc += base[(size_t)d * DIM];
    wvt[c * NH + n] = acc;
  }
}

// ---- kernel XV: fused x->bf16 conversion + v-sum.
// one wave per pixel: xb[p][c] = bf16(x[p][c]);  vs[(b*8+n)*1024+xy] = sum_c x[p][c]*wvt[c][n]
__global__ __launch_bounds__(256) void k_xv(const float* __restrict__ x,
                                            const float* __restrict__ wvt,
                                            short* __restrict__ xb,
                                            float* __restrict__ vs) {
  const int t = threadIdx.x, wave = t >> 6, lane = t & 63;
  const int p = blockIdx.x * 4 + wave;
  const float* xp = x + (size_t)p * DIM + lane * 8;
  const f32x4 x0 = *(const f32x4*)(xp);
  const f32x4 x1 = *(const f32x4*)(xp + 4);
  float xf[8];
  B8 u;
#pragma unroll
  for (int j = 0; j < 4; ++j) {
    xf[j] = x0[j]; xf[4 + j] = x1[j];
    u.h[j] = __float2bfloat16(x0[j]); u.h[4 + j] = __float2bfloat16(x1[j]);
  }
  *(s16x8*)(xb + (size_t)p * DIM + lane * 8) = u.v;    // 1 KB/wave contiguous
  float acc[8] = {0.f,0.f,0.f,0.f,0.f,0.f,0.f,0.f};
  const float* wp = wvt + lane * 64;                   // c=8l..8l+8, n=0..8
#pragma unroll
  for (int cc = 0; cc < 8; ++cc) {
    const f32x4 a = *(const f32x4*)(wp + cc * 8);
    const f32x4 b = *(const f32x4*)(wp + cc * 8 + 4);
#pragma unroll
    for (int j = 0; j < 4; ++j) { acc[j] += xf[cc] * a[j]; acc[4 + j] += xf[cc] * b[j]; }
  }
#pragma unroll
  for (int off = 32; off >= 1; off >>= 1) {
#pragma unroll
    for (int j = 0; j < 8; ++j) acc[j] += __shfl_xor(acc[j], off, 64);
  }
  if (lane == 0) {
    const int b_ = p >> 10, xy = p & 1023;
#pragma unroll
    for (int j = 0; j < 8; ++j) vs[(size_t)(b_ * NH + j) * HW + xy] = acc[j];
  }
}

// ---- kernel QKO: fused q/k projection + head-dot + softmax + output write.
// ONE WAVE PER (32-pixel h-row, head): grid (256, 8), block 64. 2048 independent
// blocks (8/CU) with zero barriers between waves -> staggered finish times, so
// NT-store streams of finished blocks overlap the MFMA/load phases of others.
__global__ __launch_bounds__(64) void k_qko(const short* __restrict__ xb,
                                            const short* __restrict__ wqb,
                                            const short* __restrict__ wkb,
                                            const float* __restrict__ vs,
                                            float* __restrict__ out) {
  __shared__ float sm[32];
  __shared__ float probs[32];
  const int lane = threadIdx.x;
  const int lrow = lane & 15, quad = lane >> 4;
  const int pix0 = blockIdx.x * 32;
  const int head = blockIdx.y;
  const int b_ = pix0 >> 10, hw0 = pix0 & 1023;
  const int bn = b_ * NH + head;

  // prefetch vs panel row for the store phase (16 floats/lane, covers xy 0..1023)
  f32x4 vsr[4];
  const float* vp = vs + (size_t)bn * HW + lane * 4;
#pragma unroll
  for (int c = 0; c < 4; ++c) vsr[c] = *(const f32x4*)(vp + c * 256);

  const short* xr0 = xb + (size_t)(pix0 + lrow) * DIM + quad * 8;
  const short* xr1 = xr0 + 16 * DIM;
  const short* qb = wqb + (size_t)(head * DH + lrow) * DIM + quad * 8;
  const short* kb = wkb + (size_t)(head * DH + lrow) * DIM + quad * 8;

  f32x4 accq[2][4], acck[2][4];
#pragma unroll
  for (int s = 0; s < 2; ++s)
#pragma unroll
    for (int o = 0; o < 4; ++o) { accq[s][o] = (f32x4)0.f; acck[s][o] = (f32x4)0.f; }

#pragma unroll 2
  for (int ks = 0; ks < 16; ++ks) {
    const int off = ks * 32;
    const s16x8 a0 = *(const s16x8*)(xr0 + off);
    const s16x8 a1 = *(const s16x8*)(xr1 + off);
#pragma unroll
    for (int o = 0; o < 4; ++o) {
      const s16x8 bq = *(const s16x8*)(qb + o * 16 * DIM + off);
      accq[0][o] = __builtin_amdgcn_mfma_f32_16x16x32_bf16(a0, bq, accq[0][o], 0, 0, 0);
      accq[1][o] = __builtin_amdgcn_mfma_f32_16x16x32_bf16(a1, bq, accq[1][o], 0, 0, 0);
      const s16x8 bk = *(const s16x8*)(kb + o * 16 * DIM + off);
      acck[0][o] = __builtin_amdgcn_mfma_f32_16x16x32_bf16(a0, bk, acck[0][o], 0, 0, 0);
      acck[1][o] = __builtin_amdgcn_mfma_f32_16x16x32_bf16(a1, bk, acck[1][o], 0, 0, 0);
    }
  }

  // per-row dot over the 64 head channels: sum 4 col-subtiles + 16 col-lanes.
  // C layout: col = lane&15 (out-ch), row = quad*4 + reg (pixel) — reduce over lrow.
#pragma unroll
  for (int s = 0; s < 2; ++s) {
#pragma unroll
    for (int j = 0; j < 4; ++j) {
      float pr = accq[s][0][j] * acck[s][0][j] + accq[s][1][j] * acck[s][1][j]
               + accq[s][2][j] * acck[s][2][j] + accq[s][3][j] * acck[s][3][j];
      pr += __shfl_xor(pr, 1, 64);
      pr += __shfl_xor(pr, 2, 64);
      pr += __shfl_xor(pr, 4, 64);
      pr += __shfl_xor(pr, 8, 64);
      if (lrow == 0) sm[s * 16 + quad * 4 + j] = pr * 0.125f;  // scale = 1/8
    }
  }
  __syncthreads();   // single-wave block: just LDS visibility

  // softmax over the 32 w-positions; both 32-lane halves hold identical copies.
  const float v = sm[lane & 31];
  float m = v;
#pragma unroll
  for (int off = 1; off <= 16; off <<= 1) m = fmaxf(m, __shfl_xor(m, off, 64));
  const float e = __expf(v - m);
  float se = e;
#pragma unroll
  for (int off = 1; off <= 16; off <<= 1) se += __shfl_xor(se, off, 64);
  if (lane < 32) probs[lane] = e / se;
  __syncthreads();

  // store phase: out[bn][hw0+r][xy] = probs[r] * vs[bn][xy], NT float4 stores.
  // wave covers xy via 4 chunks of 256: xy = c*256 + lane*4 -> 1 KB contiguous/store.
  float* op = out + (size_t)bn * HW * HW + (size_t)hw0 * HW + lane * 4;
#pragma unroll 4
  for (int r = 0; r < 32; ++r) {
    const float w = probs[r];
    float* orow = op + (size_t)r * HW;
#pragma unroll
    for (int c = 0; c < 4; ++c) {
      f32x4 o;
#pragma unroll
      for (int j = 0; j < 4; ++j) o[j] = w * vsr[c][j];
      __builtin_nontemporal_store(o, (f32x4*)(orow + c * 256));
    }
  }
}

extern "C" void kernel_launch(void* const* d_in, const int* in_sizes, int n_in,
                              void* d_out, int out_size, void* d_ws, size_t ws_size,
                              hipStream_t stream) {
  const float* x  = (const float*)d_in[0];
  const float* wq = (const float*)d_in[1];
  const float* wk = (const float*)d_in[2];
  const float* wv = (const float*)d_in[3];
  float* out = (float*)d_out;

  float* wvt = (float*)d_ws;                 // 4096 floats   [c][n]
  float* vs  = wvt + 4096;                   // 65536 floats  [bn][xy]
  short* xb  = (short*)(vs + 65536);         // 8192*512 bf16 (8 MB), 16B-aligned
  short* wqb = xb + (size_t)NPIX * DIM;      // 512*512 bf16
  short* wkb = wqb + DIM * DIM;              // 512*512 bf16

  hipLaunchKernelGGL(k_prep, dim3(272), dim3(256), 0, stream, wq, wk, wv, wqb, wkb, wvt);
  hipLaunchKernelGGL(k_xv, dim3(NPIX / 4), dim3(256), 0, stream, x, wvt, xb, vs);
  hipLaunchKernelGGL(k_qko, dim3(NPIX / 32, NH), dim3(64), 0, stream, xb, wqb, wkb, vs, out);
}

// Round 4
// 332.760 us; speedup vs baseline: 1.0346x; 1.0103x over previous
//
#include <hip/hip_runtime.h>
#include <hip/hip_bf16.h>

#define DIM 512
#define NH 8
#define DH 64
#define HW 1024     // 32*32
#define NPIX 8192   // 8*32*32

typedef __attribute__((ext_vector_type(8))) short s16x8;
typedef __attribute__((ext_vector_type(4))) float f32x4;

union B8 { s16x8 v; __hip_bfloat16 h[8]; };

// ---- kernel P: weight prep.
// blocks [0,128):   wq -> wqb (bf16, same [out][in] layout)
// blocks [128,256): wk -> wkb
// blocks [256,272): wvt[c*8+n] = sum_d wv[n*64+d][c]  (column sums, [c][n] layout)
__global__ __launch_bounds__(256) void k_prep(const float* __restrict__ wq,
                                              const float* __restrict__ wk,
                                              const float* __restrict__ wv,
                                              short* __restrict__ wqb,
                                              short* __restrict__ wkb,
                                              float* __restrict__ wvt) {
  const int b = blockIdx.x, t = threadIdx.x;
  if (b < 256) {
    const int half = b >> 7;                 // 0: wq, 1: wk
    const float* src = half ? wk : wq;
    short* dst = half ? wkb : wqb;
    const int idx = ((b & 127) * 256 + t) * 8;
    const f32x4 a = *(const f32x4*)(src + idx);
    const f32x4 c = *(const f32x4*)(src + idx + 4);
    B8 u;
#pragma unroll
    for (int m = 0; m < 4; ++m) { u.h[m] = __float2bfloat16(a[m]); u.h[4 + m] = __float2bfloat16(c[m]); }
    *(s16x8*)(dst + idx) = u.v;
  } else {
    const int i = b - 256;
    const int n = t >> 5, c = i * 32 + (t & 31);   // lanes 0-31: consecutive c -> coalesced
    const float* base = wv + (size_t)n * DH * DIM + c;
    float acc = 0.f;
#pragma unroll 8
    for (int d = 0; d < DH; ++d) acc += base[(size_t)d * DIM];
    wvt[c * NH + n] = acc;
  }
}

// ---- kernel XV: fused x->bf16 conversion + v-sum.
// one wave per pixel: xb[p][c] = bf16(x[p][c]);  vs[(b*8+n)*1024+xy] = sum_c x[p][c]*wvt[c][n]
__global__ __launch_bounds__(256) void k_xv(const float* __restrict__ x,
                                            const float* __restrict__ wvt,
                                            short* __restrict__ xb,
                                            float* __restrict__ vs) {
  const int t = threadIdx.x, wave = t >> 6, lane = t & 63;
  const int p = blockIdx.x * 4 + wave;
  const float* xp = x + (size_t)p * DIM + lane * 8;
  const f32x4 x0 = *(const f32x4*)(xp);
  const f32x4 x1 = *(const f32x4*)(xp + 4);
  float xf[8];
  B8 u;
#pragma unroll
  for (int j = 0; j < 4; ++j) {
    xf[j] = x0[j]; xf[4 + j] = x1[j];
    u.h[j] = __float2bfloat16(x0[j]); u.h[4 + j] = __float2bfloat16(x1[j]);
  }
  *(s16x8*)(xb + (size_t)p * DIM + lane * 8) = u.v;    // 1 KB/wave contiguous
  float acc[8] = {0.f,0.f,0.f,0.f,0.f,0.f,0.f,0.f};
  const float* wp = wvt + lane * 64;                   // c=8l..8l+8, n=0..8
#pragma unroll
  for (int cc = 0; cc < 8; ++cc) {
    const f32x4 a = *(const f32x4*)(wp + cc * 8);
    const f32x4 b = *(const f32x4*)(wp + cc * 8 + 4);
#pragma unroll
    for (int j = 0; j < 4; ++j) { acc[j] += xf[cc] * a[j]; acc[4 + j] += xf[cc] * b[j]; }
  }
#pragma unroll
  for (int off = 32; off >= 1; off >>= 1) {
#pragma unroll
    for (int j = 0; j < 8; ++j) acc[j] += __shfl_xor(acc[j], off, 64);
  }
  if (lane == 0) {
    const int b_ = p >> 10, xy = p & 1023;
#pragma unroll
    for (int j = 0; j < 8; ++j) vs[(size_t)(b_ * NH + j) * HW + xy] = acc[j];
  }
}

// ---- kernel QKO: fused q/k projection + head-dot + softmax + output write.
// ONE WAVE PER (32-pixel h-row, head): grid (256, 8), block 64. 2048 independent
// blocks (8/CU), no inter-wave coupling. A/B vs round 3: PLAIN stores instead of
// nontemporal (NT write path on gfx950 is unmeasured; the 6.4 TB/s store ceiling
// was proven with plain stores by the poison fills themselves).
__global__ __launch_bounds__(64) void k_qko(const short* __restrict__ xb,
                                            const short* __restrict__ wqb,
                                            const short* __restrict__ wkb,
                                            const float* __restrict__ vs,
                                            float* __restrict__ out) {
  __shared__ float sm[32];
  __shared__ float probs[32];
  const int lane = threadIdx.x;
  const int lrow = lane & 15, quad = lane >> 4;
  const int pix0 = blockIdx.x * 32;
  const int head = blockIdx.y;
  const int b_ = pix0 >> 10, hw0 = pix0 & 1023;
  const int bn = b_ * NH + head;

  // prefetch vs panel row for the store phase (16 floats/lane, covers xy 0..1023)
  f32x4 vsr[4];
  const float* vp = vs + (size_t)bn * HW + lane * 4;
#pragma unroll
  for (int c = 0; c < 4; ++c) vsr[c] = *(const f32x4*)(vp + c * 256);

  const short* xr0 = xb + (size_t)(pix0 + lrow) * DIM + quad * 8;
  const short* xr1 = xr0 + 16 * DIM;
  const short* qb = wqb + (size_t)(head * DH + lrow) * DIM + quad * 8;
  const short* kb = wkb + (size_t)(head * DH + lrow) * DIM + quad * 8;

  f32x4 accq[2][4], acck[2][4];
#pragma unroll
  for (int s = 0; s < 2; ++s)
#pragma unroll
    for (int o = 0; o < 4; ++o) { accq[s][o] = (f32x4)0.f; acck[s][o] = (f32x4)0.f; }

#pragma unroll 2
  for (int ks = 0; ks < 16; ++ks) {
    const int off = ks * 32;
    const s16x8 a0 = *(const s16x8*)(xr0 + off);
    const s16x8 a1 = *(const s16x8*)(xr1 + off);
#pragma unroll
    for (int o = 0; o < 4; ++o) {
      const s16x8 bq = *(const s16x8*)(qb + o * 16 * DIM + off);
      accq[0][o] = __builtin_amdgcn_mfma_f32_16x16x32_bf16(a0, bq, accq[0][o], 0, 0, 0);
      accq[1][o] = __builtin_amdgcn_mfma_f32_16x16x32_bf16(a1, bq, accq[1][o], 0, 0, 0);
      const s16x8 bk = *(const s16x8*)(kb + o * 16 * DIM + off);
      acck[0][o] = __builtin_amdgcn_mfma_f32_16x16x32_bf16(a0, bk, acck[0][o], 0, 0, 0);
      acck[1][o] = __builtin_amdgcn_mfma_f32_16x16x32_bf16(a1, bk, acck[1][o], 0, 0, 0);
    }
  }

  // per-row dot over the 64 head channels: sum 4 col-subtiles + 16 col-lanes.
  // C layout: col = lane&15 (out-ch), row = quad*4 + reg (pixel) — reduce over lrow.
#pragma unroll
  for (int s = 0; s < 2; ++s) {
#pragma unroll
    for (int j = 0; j < 4; ++j) {
      float pr = accq[s][0][j] * acck[s][0][j] + accq[s][1][j] * acck[s][1][j]
               + accq[s][2][j] * acck[s][2][j] + accq[s][3][j] * acck[s][3][j];
      pr += __shfl_xor(pr, 1, 64);
      pr += __shfl_xor(pr, 2, 64);
      pr += __shfl_xor(pr, 4, 64);
      pr += __shfl_xor(pr, 8, 64);
      if (lrow == 0) sm[s * 16 + quad * 4 + j] = pr * 0.125f;  // scale = 1/8
    }
  }
  __syncthreads();   // single-wave block: just LDS visibility

  // softmax over the 32 w-positions; both 32-lane halves hold identical copies.
  const float v = sm[lane & 31];
  float m = v;
#pragma unroll
  for (int off = 1; off <= 16; off <<= 1) m = fmaxf(m, __shfl_xor(m, off, 64));
  const float e = __expf(v - m);
  float se = e;
#pragma unroll
  for (int off = 1; off <= 16; off <<= 1) se += __shfl_xor(se, off, 64);
  if (lane < 32) probs[lane] = e / se;
  __syncthreads();

  // store phase: out[bn][hw0+r][xy] = probs[r] * vs[bn][xy], PLAIN float4 stores.
  // wave covers xy via 4 chunks of 256: per row the wave writes 4 KB contiguous;
  // over r the wave streams a 128 KB contiguous panel.
  float* op = out + (size_t)bn * HW * HW + (size_t)hw0 * HW + lane * 4;
#pragma unroll 4
  for (int r = 0; r < 32; ++r) {
    const float w = probs[r];
    float* orow = op + (size_t)r * HW;
#pragma unroll
    for (int c = 0; c < 4; ++c) {
      f32x4 o;
#pragma unroll
      for (int j = 0; j < 4; ++j) o[j] = w * vsr[c][j];
      *(f32x4*)(orow + c * 256) = o;
    }
  }
}

extern "C" void kernel_launch(void* const* d_in, const int* in_sizes, int n_in,
                              void* d_out, int out_size, void* d_ws, size_t ws_size,
                              hipStream_t stream) {
  const float* x  = (const float*)d_in[0];
  const float* wq = (const float*)d_in[1];
  const float* wk = (const float*)d_in[2];
  const float* wv = (const float*)d_in[3];
  float* out = (float*)d_out;

  float* wvt = (float*)d_ws;                 // 4096 floats   [c][n]
  float* vs  = wvt + 4096;                   // 65536 floats  [bn][xy]
  short* xb  = (short*)(vs + 65536);         // 8192*512 bf16 (8 MB), 16B-aligned
  short* wqb = xb + (size_t)NPIX * DIM;      // 512*512 bf16
  short* wkb = wqb + DIM * DIM;              // 512*512 bf16

  hipLaunchKernelGGL(k_prep, dim3(272), dim3(256), 0, stream, wq, wk, wv, wqb, wkb, wvt);
  hipLaunchKernelGGL(k_xv, dim3(NPIX / 4), dim3(256), 0, stream, x, wvt, xb, vs);
  hipLaunchKernelGGL(k_qko, dim3(NPIX / 32, NH), dim3(64), 0, stream, xb, wqb, wkb, vs, out);
}